// Round 2
// baseline (293.590 us; speedup 1.0000x reference)
//
#include <hip/hip_runtime.h>

typedef unsigned short ushort_t;
typedef unsigned int   uint32;
typedef __bf16 bf16_t;
typedef bf16_t bf16x8 __attribute__((ext_vector_type(8)));
typedef float  f32x4  __attribute__((ext_vector_type(4)));

#define N_TOK 4096
#define C_DIM 128
#define NTOT  8192
#define THRESH2 64.0f

// workspace layout (bytes)
#define XF_OFF  (0u)                      // bf16 [8192][128]   token-major xf (bf16-converted)
#define YT_OFF  (2u<<20)                  // bf16 [2][128][4096] y transposed
#define ET_OFF  (4u<<20)                  // bf16 [2][128][4096] E transposed
#define YF_OFF  (6u<<20)                  // f32  [8192][128]   y fp32
#define XE_OFF  (10u<<20)                 // f32  [8192][128]   xe
#define SQ_OFF  (14u<<20)                 // f32  [8192]
#define S_OFF   ((14u<<20) + 32768u)      // f32  [8192] rowsums
#define BN_OFF  ((14u<<20) + 65536u)      // f32  [256]  sum/sumsq
#define H_OFF   (16u<<20)                 // bf16 [2][4096][4096]
#define WS_NEED ((size_t)(80u<<20))

__device__ __forceinline__ float b2f(ushort_t u){ return __uint_as_float(((uint32)u)<<16); }
__device__ __forceinline__ ushort_t f2b(float f){
    uint32 u = __float_as_uint(f);
    u += 0x7fffu + ((u>>16)&1u);
    return (ushort_t)(u>>16);
}

// K1: x fp32 [B,C,N] -> Xf bf16 [B*N, C], LDS 32x32 tile transpose
__global__ __launch_bounds__(256) void k_transpose(const float* __restrict__ x,
                                                   ushort_t* __restrict__ Xf){
    __shared__ ushort_t tile[32][33];
    int tx = threadIdx.x, ty = threadIdx.y;
    int n0 = blockIdx.x*32, c0 = blockIdx.y*32, b = blockIdx.z;
    #pragma unroll
    for (int k=0;k<4;k++){
        int c = ty + 8*k;
        tile[c][tx] = f2b(x[(size_t)(b*C_DIM + c0 + c)*N_TOK + n0 + tx]);
    }
    __syncthreads();
    #pragma unroll
    for (int k=0;k<4;k++){
        int nl = ty + 8*k;
        Xf[(size_t)(b*N_TOK + n0 + nl)*C_DIM + c0 + tx] = tile[tx][nl];
    }
}

// K2: y = xf @ W^T + b (fp32 + bf16-transposed copies), and sq = sum(xf^2)
__global__ __launch_bounds__(256) void k_fc(const ushort_t* __restrict__ Xf,
                                            const float* __restrict__ W,
                                            const float* __restrict__ bfc,
                                            float* __restrict__ Yf,
                                            ushort_t* __restrict__ Yt,
                                            float* __restrict__ sq){
    __shared__ ushort_t Wt[C_DIM*132];   // W transposed (bf16): Wt[c][d]
    __shared__ float    Xs[16*132];
    int tid = threadIdx.x;
    int t0 = blockIdx.x * 16;
    for (int k=0;k<64;k++){
        int idx = tid + 256*k;
        int d = idx >> 7, c = idx & 127;
        Wt[c*132 + d] = f2b(W[idx]);
    }
    #pragma unroll
    for (int k=0;k<8;k++){
        int idx = tid + 256*k;
        int tl = idx >> 7, c = idx & 127;
        Xs[tl*132 + c] = b2f(Xf[(size_t)(t0 + tl)*C_DIM + c]);
    }
    __syncthreads();
    int tok = tid & 15;
    int d0 = (tid >> 4) * 8;
    int ft = t0 + tok;
    float acc[8] = {0,0,0,0,0,0,0,0};
    float sacc = 0.f;
    for (int c=0;c<C_DIM;c++){
        float xv = Xs[tok*132 + c];
        sacc = fmaf(xv, xv, sacc);
        const ushort_t* wr = &Wt[c*132 + d0];
        #pragma unroll
        for (int j=0;j<8;j++) acc[j] = fmaf(xv, b2f(wr[j]), acc[j]);
    }
    int b = ft >> 12, n = ft & 4095;
    #pragma unroll
    for (int j=0;j<8;j++){
        float y = acc[j] + bfc[d0+j];
        Yf[(size_t)ft*C_DIM + d0 + j] = y;
        Yt[(size_t)(b*C_DIM + d0 + j)*N_TOK + n] = f2b(y);
    }
    if ((tid >> 4) == 0) sq[ft] = sacc;
}

// K3: G = Xf·Xf^T (64x64 tile, MFMA), H = (sq_i+sq_j-2G < 64), rowsums via atomics
__global__ __launch_bounds__(256) void k_gram(const ushort_t* __restrict__ Xf,
                                              const float* __restrict__ sq,
                                              ushort_t* __restrict__ H,
                                              float* __restrict__ s){
    __shared__ ushort_t Al[64*136];
    __shared__ ushort_t Bl[64*136];
    int tid = threadIdx.x;
    int i0 = blockIdx.x * 64, j0 = blockIdx.y * 64, b = blockIdx.z;
    const ushort_t* XfA = Xf + (size_t)(b*N_TOK + i0)*C_DIM;
    const ushort_t* XfB = Xf + (size_t)(b*N_TOK + j0)*C_DIM;
    #pragma unroll
    for (int k=0;k<4;k++){
        int q = tid + 256*k;
        int row = q >> 4, cp = q & 15;
        *(uint4*)(&Al[row*136 + cp*8]) = *(const uint4*)(XfA + row*C_DIM + cp*8);
        *(uint4*)(&Bl[row*136 + cp*8]) = *(const uint4*)(XfB + row*C_DIM + cp*8);
    }
    __syncthreads();
    int w = tid >> 6, lane = tid & 63;
    int qd = lane >> 4, m = lane & 15;
    f32x4 acc[4] = {{0,0,0,0},{0,0,0,0},{0,0,0,0},{0,0,0,0}};
    #pragma unroll
    for (int kc=0;kc<4;kc++){
        bf16x8 af = *(const bf16x8*)(&Al[(w*16 + m)*136 + kc*32 + qd*8]);
        #pragma unroll
        for (int t=0;t<4;t++){
            bf16x8 bfr = *(const bf16x8*)(&Bl[(t*16 + m)*136 + kc*32 + qd*8]);
            acc[t] = __builtin_amdgcn_mfma_f32_16x16x32_bf16(af, bfr, acc[t], 0, 0, 0);
        }
    }
    int ib = i0 + w*16 + qd*4;
    float sqi[4];
    #pragma unroll
    for (int r=0;r<4;r++) sqi[r] = sq[b*N_TOK + ib + r];
    float rs[4] = {0,0,0,0};
    size_t Hbase = (size_t)b * N_TOK * N_TOK;
    #pragma unroll
    for (int t=0;t<4;t++){
        float sqj = sq[b*N_TOK + j0 + t*16 + m];
        #pragma unroll
        for (int r=0;r<4;r++){
            float d2 = sqi[r] + sqj - 2.0f*acc[t][r];
            bool hit = d2 < THRESH2;
            H[Hbase + (size_t)(ib + r)*N_TOK + j0 + t*16 + m] = hit ? (ushort_t)0x3f80 : (ushort_t)0;
            rs[r] += hit ? 1.0f : 0.0f;
        }
    }
    #pragma unroll
    for (int r=0;r<4;r++){
        float v = rs[r];
        v += __shfl_xor(v, 1);
        v += __shfl_xor(v, 2);
        v += __shfl_xor(v, 4);
        v += __shfl_xor(v, 8);
        if (m == 0) atomicAdd(&s[b*N_TOK + ib + r], v);
    }
}

// K4: Z = H @ V (V given transposed [c][k]); MODE 0: Et = (Z/s)^T bf16; MODE 1: Xe = Yf + Z/s
template<int MODE>
__global__ __launch_bounds__(512) void k_agg(const ushort_t* __restrict__ Hp,
                                             const ushort_t* __restrict__ Vt,
                                             const float* __restrict__ s,
                                             const float* __restrict__ Yf,
                                             ushort_t* __restrict__ Et,
                                             float* __restrict__ Xe){
    int tid = threadIdx.x;
    int b = blockIdx.z;
    int i0 = blockIdx.x * 32;
    int w = tid >> 6, lane = tid & 63;
    int qd = lane >> 4, m = lane & 15;
    int rowT = w & 1;
    int c0 = (w >> 1) * 32;
    const bf16_t* Hrow = (const bf16_t*)Hp + (size_t)b*N_TOK*N_TOK
                       + (size_t)(i0 + rowT*16 + m)*N_TOK + qd*8;
    const bf16_t* V0 = (const bf16_t*)Vt + (size_t)(b*C_DIM + c0 + m)*N_TOK + qd*8;
    const bf16_t* V1 = V0 + (size_t)16*N_TOK;
    f32x4 acc0 = {0,0,0,0}, acc1 = {0,0,0,0};
    #pragma unroll 8
    for (int kc=0;kc<N_TOK;kc+=32){
        bf16x8 af = *(const bf16x8*)(Hrow + kc);
        bf16x8 b0 = *(const bf16x8*)(V0 + kc);
        bf16x8 b1 = *(const bf16x8*)(V1 + kc);
        acc0 = __builtin_amdgcn_mfma_f32_16x16x32_bf16(af, b0, acc0, 0, 0, 0);
        acc1 = __builtin_amdgcn_mfma_f32_16x16x32_bf16(af, b1, acc1, 0, 0, 0);
    }
    int ib = i0 + rowT*16 + qd*4;
    float rn[4];
    #pragma unroll
    for (int r=0;r<4;r++){
        float sv = s[b*N_TOK + ib + r];
        rn[r] = (sv > 0.f) ? (1.0f/sv) : 0.0f;
    }
    if (MODE == 0){
        #pragma unroll
        for (int t=0;t<2;t++){
            f32x4 a = t ? acc1 : acc0;
            int col = c0 + t*16 + m;
            ushort_t pk[4];
            #pragma unroll
            for (int r=0;r<4;r++) pk[r] = f2b(a[r]*rn[r]);
            uint2 u;
            u.x = (uint32)pk[0] | ((uint32)pk[1]<<16);
            u.y = (uint32)pk[2] | ((uint32)pk[3]<<16);
            *(uint2*)(Et + (size_t)(b*C_DIM + col)*N_TOK + ib) = u;
        }
    } else {
        #pragma unroll
        for (int t=0;t<2;t++){
            f32x4 a = t ? acc1 : acc0;
            int col = c0 + t*16 + m;
            #pragma unroll
            for (int r=0;r<4;r++){
                size_t idx = (size_t)(b*N_TOK + ib + r)*C_DIM + col;
                Xe[idx] = Yf[idx] + a[r]*rn[r];
            }
        }
    }
}

// K5: per-channel sum & sumsq over all 8192 tokens
__global__ __launch_bounds__(256) void k_bnstats(const float* __restrict__ Xe,
                                                 float* __restrict__ bn){
    __shared__ float r1[256], r2[256];
    int tid = threadIdx.x;
    int c = tid & 127, h = tid >> 7;
    int tb = blockIdx.x * 64;
    float sm = 0.f, ss = 0.f;
    for (int tt = tb + h; tt < tb + 64; tt += 2){
        float v = Xe[(size_t)tt*C_DIM + c];
        sm += v; ss = fmaf(v, v, ss);
    }
    r1[tid] = sm; r2[tid] = ss;
    __syncthreads();
    if (tid < 128){
        atomicAdd(&bn[c],       r1[tid] + r1[tid+128]);
        atomicAdd(&bn[128 + c], r2[tid] + r2[tid+128]);
    }
}

// K6: BN affine + SiLU + transpose back to [B,C,N], fp32 out
__global__ __launch_bounds__(256) void k_out(const float* __restrict__ Xe,
                                             const float* __restrict__ bn,
                                             const float* __restrict__ gamma,
                                             const float* __restrict__ beta,
                                             float* __restrict__ out){
    __shared__ float tile[32][33];
    int tx = threadIdx.x, ty = threadIdx.y;
    int n0 = blockIdx.x*32, c0 = blockIdx.y*32, b = blockIdx.z;
    int c = c0 + tx;
    float inv = 1.0f / (float)NTOT;
    float mean = bn[c] * inv;
    float var  = bn[128 + c]*inv - mean*mean;
    float scale = gamma[c] * rsqrtf(var + 1e-5f);
    float shift = beta[c] - mean*scale;
    #pragma unroll
    for (int k=0;k<4;k++){
        int nl = ty + 8*k;
        float v = Xe[(size_t)(b*N_TOK + n0 + nl)*C_DIM + c];
        v = scale*v + shift;
        float sg = 1.0f/(1.0f + __expf(-v));
        tile[tx][nl] = v * sg;
    }
    __syncthreads();
    #pragma unroll
    for (int k=0;k<4;k++){
        int cl = ty + 8*k;
        out[(size_t)(b*C_DIM + c0 + cl)*N_TOK + n0 + tx] = tile[cl][tx];
    }
}

extern "C" void kernel_launch(void* const* d_in, const int* in_sizes, int n_in,
                              void* d_out, int out_size, void* d_ws, size_t ws_size,
                              hipStream_t stream){
    if (ws_size < WS_NEED) return;
    const float* x     = (const float*)d_in[0];
    const float* W     = (const float*)d_in[1];
    const float* bfc   = (const float*)d_in[2];
    const float* gamma = (const float*)d_in[3];
    const float* beta  = (const float*)d_in[4];
    char* ws = (char*)d_ws;
    ushort_t* Xf = (ushort_t*)(ws + XF_OFF);
    ushort_t* Yt = (ushort_t*)(ws + YT_OFF);
    ushort_t* Et = (ushort_t*)(ws + ET_OFF);
    float*    Yf = (float*)(ws + YF_OFF);
    float*    Xe = (float*)(ws + XE_OFF);
    float*    sq = (float*)(ws + SQ_OFF);
    float*    s  = (float*)(ws + S_OFF);
    float*    bn = (float*)(ws + BN_OFF);
    ushort_t* H  = (ushort_t*)(ws + H_OFF);
    float* out = (float*)d_out;

    hipMemsetAsync(ws + S_OFF, 0, 32768 + 33792, stream);  // zero s + bn
    k_transpose<<<dim3(128,4,2), dim3(32,8), 0, stream>>>(x, Xf);
    k_fc<<<dim3(512), dim3(256), 0, stream>>>(Xf, W, bfc, Yf, Yt, sq);
    k_gram<<<dim3(64,64,2), dim3(256), 0, stream>>>(Xf, sq, H, s);
    k_agg<0><<<dim3(128,1,2), dim3(512), 0, stream>>>(H, Yt, s, Yf, Et, Xe);
    k_agg<1><<<dim3(128,1,2), dim3(512), 0, stream>>>(H, Et, s, Yf, Et, Xe);
    k_bnstats<<<dim3(128), dim3(256), 0, stream>>>(Xe, bn);
    k_out<<<dim3(128,4,2), dim3(32,8), 0, stream>>>(Xe, bn, gamma, beta, out);
}

// Round 3
// 130.928 us; speedup vs baseline: 2.2424x; 2.2424x over previous
//
#include <hip/hip_runtime.h>

typedef unsigned short ushort_t;
typedef unsigned int   uint32;
typedef unsigned long long u64;
typedef __bf16 bf16_t;
typedef bf16_t bf16x8 __attribute__((ext_vector_type(8)));
typedef float  f32x4  __attribute__((ext_vector_type(4)));

#define N_TOK 4096
#define C_DIM 128
#define NTOT  8192
#define THRESH2 64.0f

// workspace layout (bytes)
#define XF_OFF  (0u)                      // bf16 [8192][128]  token-major xf (bf16)
#define YF_OFF  (2u<<20)                  // f32  [8192][128]  y
#define EF_OFF  (6u<<20)                  // f32  [8192][128]  E
#define XE_OFF  (10u<<20)                 // f32  [8192][128]  xe
#define SQ_OFF  (14u<<20)                 // f32  [8192]
#define BN_OFF  ((14u<<20) + 32768u)      // f32  [256] sum/sumsq
#define HB_OFF  (16u<<20)                 // u64  [8192][64] bitmask rows
#define WS_NEED ((size_t)(24u<<20))

__device__ __forceinline__ float b2f(ushort_t u){ return __uint_as_float(((uint32)u)<<16); }
__device__ __forceinline__ ushort_t f2b(float f){
    uint32 u = __float_as_uint(f);
    u += 0x7fffu + ((u>>16)&1u);
    return (ushort_t)(u>>16);
}
__device__ __forceinline__ u64 shfl_u64(u64 v, int src){
    uint32 lo = (uint32)v, hi = (uint32)(v>>32);
    lo = __shfl(lo, src); hi = __shfl(hi, src);
    return ((u64)hi<<32)|lo;
}
__device__ __forceinline__ u64 shfl_xor_u64(u64 v, int m){
    uint32 lo = (uint32)v, hi = (uint32)(v>>32);
    lo = __shfl_xor(lo, m); hi = __shfl_xor(hi, m);
    return ((u64)hi<<32)|lo;
}

// K1: x fp32 [B,C,N] -> Xf bf16 [B*N, C], LDS 32x32 tile transpose
__global__ __launch_bounds__(256) void k_transpose(const float* __restrict__ x,
                                                   ushort_t* __restrict__ Xf){
    __shared__ ushort_t tile[32][33];
    int tx = threadIdx.x, ty = threadIdx.y;
    int n0 = blockIdx.x*32, c0 = blockIdx.y*32, b = blockIdx.z;
    #pragma unroll
    for (int k=0;k<4;k++){
        int c = ty + 8*k;
        tile[c][tx] = f2b(x[(size_t)(b*C_DIM + c0 + c)*N_TOK + n0 + tx]);
    }
    __syncthreads();
    #pragma unroll
    for (int k=0;k<4;k++){
        int nl = ty + 8*k;
        Xf[(size_t)(b*N_TOK + n0 + nl)*C_DIM + c0 + tx] = tile[tx][nl];
    }
}

// K2: y = xf @ W^T + b (fp32), and sq = sum(xf^2)
__global__ __launch_bounds__(256) void k_fc(const ushort_t* __restrict__ Xf,
                                            const float* __restrict__ W,
                                            const float* __restrict__ bfc,
                                            float* __restrict__ Yf,
                                            float* __restrict__ sq){
    __shared__ ushort_t Wt[C_DIM*132];   // W transposed (bf16): Wt[c][d]
    __shared__ float    Xs[16*132];
    int tid = threadIdx.x;
    int t0 = blockIdx.x * 16;
    for (int k=0;k<64;k++){
        int idx = tid + 256*k;
        int d = idx >> 7, c = idx & 127;
        Wt[c*132 + d] = f2b(W[idx]);
    }
    #pragma unroll
    for (int k=0;k<8;k++){
        int idx = tid + 256*k;
        int tl = idx >> 7, c = idx & 127;
        Xs[tl*132 + c] = b2f(Xf[(size_t)(t0 + tl)*C_DIM + c]);
    }
    __syncthreads();
    int tok = tid & 15;
    int d0 = (tid >> 4) * 8;
    int ft = t0 + tok;
    float acc[8] = {0,0,0,0,0,0,0,0};
    float sacc = 0.f;
    for (int c=0;c<C_DIM;c++){
        float xv = Xs[tok*132 + c];
        sacc = fmaf(xv, xv, sacc);
        const ushort_t* wr = &Wt[c*132 + d0];
        #pragma unroll
        for (int j=0;j<8;j++) acc[j] = fmaf(xv, b2f(wr[j]), acc[j]);
    }
    #pragma unroll
    for (int j=0;j<8;j++)
        Yf[(size_t)ft*C_DIM + d0 + j] = acc[j] + bfc[d0+j];
    if ((tid >> 4) == 0) sq[ft] = sacc;
}

// K3: G = Xf·Xf^T (64x64 tile, MFMA); bitpack (d2 < 64) into Hb[row][64 words]
__global__ __launch_bounds__(256) void k_gram(const ushort_t* __restrict__ Xf,
                                              const float* __restrict__ sq,
                                              u64* __restrict__ Hb){
    __shared__ ushort_t Al[64*136];
    __shared__ ushort_t Bl[64*136];
    int tid = threadIdx.x;
    int i0 = blockIdx.x * 64, j0 = blockIdx.y * 64, b = blockIdx.z;
    const ushort_t* XfA = Xf + (size_t)(b*N_TOK + i0)*C_DIM;
    const ushort_t* XfB = Xf + (size_t)(b*N_TOK + j0)*C_DIM;
    #pragma unroll
    for (int k=0;k<4;k++){
        int q = tid + 256*k;
        int row = q >> 4, cp = q & 15;
        *(uint4*)(&Al[row*136 + cp*8]) = *(const uint4*)(XfA + row*C_DIM + cp*8);
        *(uint4*)(&Bl[row*136 + cp*8]) = *(const uint4*)(XfB + row*C_DIM + cp*8);
    }
    __syncthreads();
    int w = tid >> 6, lane = tid & 63;
    int qd = lane >> 4, m = lane & 15;
    f32x4 acc[4] = {{0,0,0,0},{0,0,0,0},{0,0,0,0},{0,0,0,0}};
    #pragma unroll
    for (int kc=0;kc<4;kc++){
        bf16x8 af = *(const bf16x8*)(&Al[(w*16 + m)*136 + kc*32 + qd*8]);
        #pragma unroll
        for (int t=0;t<4;t++){
            bf16x8 bfr = *(const bf16x8*)(&Bl[(t*16 + m)*136 + kc*32 + qd*8]);
            acc[t] = __builtin_amdgcn_mfma_f32_16x16x32_bf16(af, bfr, acc[t], 0, 0, 0);
        }
    }
    int ib = i0 + w*16 + qd*4;
    float sqi[4], sqj[4];
    #pragma unroll
    for (int r=0;r<4;r++) sqi[r] = sq[b*N_TOK + ib + r];
    #pragma unroll
    for (int t=0;t<4;t++) sqj[t] = sq[b*N_TOK + j0 + t*16 + m];
    #pragma unroll
    for (int r=0;r<4;r++){
        u64 bits = 0;
        #pragma unroll
        for (int t=0;t<4;t++){
            float d2 = sqi[r] + sqj[t] - 2.0f*acc[t][r];
            if (d2 < THRESH2) bits |= (u64)1 << (t*16 + m);
        }
        bits |= shfl_xor_u64(bits, 1);
        bits |= shfl_xor_u64(bits, 2);
        bits |= shfl_xor_u64(bits, 4);
        bits |= shfl_xor_u64(bits, 8);
        if (m == 0) Hb[(size_t)(b*N_TOK + ib + r)*64 + blockIdx.y] = bits;
    }
}

// K4: sparse aggregation. One wave per output row.
// MODE 0: Out = (H @ V) / rowsum          (V = Yf -> Ef)
// MODE 1: Out = Yf + (H @ V) / rowsum     (V = Ef -> Xe)
template<int MODE>
__global__ __launch_bounds__(256) void k_aggs(const u64* __restrict__ Hb,
                                              const float* __restrict__ V,
                                              const float* __restrict__ Yf,
                                              float* __restrict__ Out){
    int tid = threadIdx.x;
    int wv = tid >> 6, lane = tid & 63;
    int row = blockIdx.x * 4 + wv;          // [0, 8192)
    int b = row >> 12;
    u64 myw = Hb[(size_t)row*64 + lane];
    int cnt = __builtin_popcountll(myw);
    cnt += __shfl_xor(cnt, 1);
    cnt += __shfl_xor(cnt, 2);
    cnt += __shfl_xor(cnt, 4);
    cnt += __shfl_xor(cnt, 8);
    cnt += __shfl_xor(cnt, 16);
    cnt += __shfl_xor(cnt, 32);
    float acc0 = 0.f, acc1 = 0.f;
    const float* Vb = V + (size_t)b*N_TOK*C_DIM;
    u64 nz = __ballot(myw != 0);            // which words have any bits
    while (nz){
        int wdi = __builtin_ctzll(nz);
        nz &= nz - 1;
        u64 mw = shfl_u64(myw, wdi);
        while (mw){
            int j = wdi*64 + __builtin_ctzll(mw);
            mw &= mw - 1;
            acc0 += Vb[(size_t)j*C_DIM + lane];
            acc1 += Vb[(size_t)j*C_DIM + lane + 64];
        }
    }
    float norm = (cnt > 0) ? (1.0f/(float)cnt) : 0.0f;
    size_t o = (size_t)row*C_DIM;
    if (MODE == 0){
        Out[o + lane]      = acc0*norm;
        Out[o + lane + 64] = acc1*norm;
    } else {
        Out[o + lane]      = Yf[o + lane]      + acc0*norm;
        Out[o + lane + 64] = Yf[o + lane + 64] + acc1*norm;
    }
}

// K5: per-channel sum & sumsq over all 8192 tokens
__global__ __launch_bounds__(256) void k_bnstats(const float* __restrict__ Xe,
                                                 float* __restrict__ bn){
    __shared__ float r1[256], r2[256];
    int tid = threadIdx.x;
    int c = tid & 127, h = tid >> 7;
    int tb = blockIdx.x * 64;
    float sm = 0.f, ss = 0.f;
    for (int tt = tb + h; tt < tb + 64; tt += 2){
        float v = Xe[(size_t)tt*C_DIM + c];
        sm += v; ss = fmaf(v, v, ss);
    }
    r1[tid] = sm; r2[tid] = ss;
    __syncthreads();
    if (tid < 128){
        atomicAdd(&bn[c],       r1[tid] + r1[tid+128]);
        atomicAdd(&bn[128 + c], r2[tid] + r2[tid+128]);
    }
}

// K6: BN affine + SiLU + transpose back to [B,C,N], fp32 out
__global__ __launch_bounds__(256) void k_out(const float* __restrict__ Xe,
                                             const float* __restrict__ bn,
                                             const float* __restrict__ gamma,
                                             const float* __restrict__ beta,
                                             float* __restrict__ out){
    __shared__ float tile[32][33];
    int tx = threadIdx.x, ty = threadIdx.y;
    int n0 = blockIdx.x*32, c0 = blockIdx.y*32, b = blockIdx.z;
    int c = c0 + tx;
    float inv = 1.0f / (float)NTOT;
    float mean = bn[c] * inv;
    float var  = bn[128 + c]*inv - mean*mean;
    float scale = gamma[c] * rsqrtf(var + 1e-5f);
    float shift = beta[c] - mean*scale;
    #pragma unroll
    for (int k=0;k<4;k++){
        int nl = ty + 8*k;
        float v = Xe[(size_t)(b*N_TOK + n0 + nl)*C_DIM + c];
        v = scale*v + shift;
        float sg = 1.0f/(1.0f + __expf(-v));
        tile[tx][nl] = v * sg;
    }
    __syncthreads();
    #pragma unroll
    for (int k=0;k<4;k++){
        int cl = ty + 8*k;
        out[(size_t)(b*C_DIM + c0 + cl)*N_TOK + n0 + tx] = tile[cl][tx];
    }
}

extern "C" void kernel_launch(void* const* d_in, const int* in_sizes, int n_in,
                              void* d_out, int out_size, void* d_ws, size_t ws_size,
                              hipStream_t stream){
    if (ws_size < WS_NEED) return;
    const float* x     = (const float*)d_in[0];
    const float* W     = (const float*)d_in[1];
    const float* bfc   = (const float*)d_in[2];
    const float* gamma = (const float*)d_in[3];
    const float* beta  = (const float*)d_in[4];
    char* ws = (char*)d_ws;
    ushort_t* Xf = (ushort_t*)(ws + XF_OFF);
    float*    Yf = (float*)(ws + YF_OFF);
    float*    Ef = (float*)(ws + EF_OFF);
    float*    Xe = (float*)(ws + XE_OFF);
    float*    sq = (float*)(ws + SQ_OFF);
    float*    bn = (float*)(ws + BN_OFF);
    u64*      Hb = (u64*)(ws + HB_OFF);
    float* out = (float*)d_out;

    hipMemsetAsync(ws + BN_OFF, 0, 1024, stream);  // zero bn
    k_transpose<<<dim3(128,4,2), dim3(32,8), 0, stream>>>(x, Xf);
    k_fc<<<dim3(512), dim3(256), 0, stream>>>(Xf, W, bfc, Yf, sq);
    k_gram<<<dim3(64,64,2), dim3(256), 0, stream>>>(Xf, sq, Hb);
    k_aggs<0><<<dim3(2048), dim3(256), 0, stream>>>(Hb, Yf, Yf, Ef);
    k_aggs<1><<<dim3(2048), dim3(256), 0, stream>>>(Hb, Ef, Yf, Xe);
    k_bnstats<<<dim3(128), dim3(256), 0, stream>>>(Xe, bn);
    k_out<<<dim3(128,4,2), dim3(32,8), 0, stream>>>(Xe, bn, gamma, beta, out);
}

// Round 4
// 118.656 us; speedup vs baseline: 2.4743x; 1.1034x over previous
//
#include <hip/hip_runtime.h>

typedef unsigned short ushort_t;
typedef unsigned int   uint32;
typedef unsigned long long u64;
typedef __bf16 bf16_t;
typedef bf16_t bf16x8 __attribute__((ext_vector_type(8)));
typedef float  f32x4  __attribute__((ext_vector_type(4)));

#define N_TOK 4096
#define C_DIM 128
#define NTOT  8192
#define THRESH2 64.0f

// workspace layout (bytes)
#define XF_OFF  (0u)                      // bf16 [8192][128]  token-major xf (bf16)
#define YF_OFF  (2u<<20)                  // f32  [8192][128]  y
#define EF_OFF  (6u<<20)                  // f32  [8192][128]  E
#define XE_OFF  (10u<<20)                 // f32  [8192][128]  xe
#define SQ_OFF  (14u<<20)                 // f32  [8192]
#define BN_OFF  ((14u<<20) + 32768u)      // f32  [256] sum/sumsq
#define HB_OFF  (16u<<20)                 // u64  [8192][64] bitmask rows
#define WS_NEED ((size_t)(24u<<20))

__device__ __forceinline__ float b2f(ushort_t u){ return __uint_as_float(((uint32)u)<<16); }
__device__ __forceinline__ ushort_t f2b(float f){
    uint32 u = __float_as_uint(f);
    u += 0x7fffu + ((u>>16)&1u);
    return (ushort_t)(u>>16);
}
__device__ __forceinline__ u64 shfl_u64(u64 v, int src){
    uint32 lo = (uint32)v, hi = (uint32)(v>>32);
    lo = __shfl(lo, src); hi = __shfl(hi, src);
    return ((u64)hi<<32)|lo;
}
__device__ __forceinline__ u64 shfl_xor_u64(u64 v, int m){
    uint32 lo = (uint32)v, hi = (uint32)(v>>32);
    lo = __shfl_xor(lo, m); hi = __shfl_xor(hi, m);
    return ((u64)hi<<32)|lo;
}

// K1: fused transpose + FC (MFMA) + sq + bn-zero.
// Reads x fp32 [B,C,N]; per block: 64 tokens. Produces Xf (bf16 token-major),
// Yf = xf@W^T + b (fp32), sq = sum(xf^2). Block 0 zeroes bn.
__global__ __launch_bounds__(256) void k_fc(const float* __restrict__ x,
                                            const float* __restrict__ W,
                                            const float* __restrict__ bfc,
                                            ushort_t* __restrict__ Xf,
                                            float* __restrict__ Yf,
                                            float* __restrict__ sq,
                                            float* __restrict__ bn){
    __shared__ ushort_t Xs[64*136];    // stride 136 u16 = 272 B (16B-aligned rows)
    __shared__ ushort_t Ws[128*136];
    int tid = threadIdx.x;
    int t0 = blockIdx.x * 64;          // flat token base (0..8191)
    int b  = t0 >> 12;
    int n0 = t0 & 4095;
    if (blockIdx.x == 0) bn[tid] = 0.f;
    // stage x -> Xs (transposed, bf16)
    const float* xb = x + (size_t)b * C_DIM * N_TOK + n0;
    #pragma unroll
    for (int k=0;k<8;k++){
        int idx = tid + 256*k;         // 2048 float4s = 64 n x 128 c
        int c = idx >> 4, n4 = (idx & 15)*4;
        float4 v = *(const float4*)(xb + (size_t)c*N_TOK + n4);
        Xs[(n4+0)*136 + c] = f2b(v.x);
        Xs[(n4+1)*136 + c] = f2b(v.y);
        Xs[(n4+2)*136 + c] = f2b(v.z);
        Xs[(n4+3)*136 + c] = f2b(v.w);
    }
    // stage W -> Ws bf16 (W[d][c] row-major 128x128)
    #pragma unroll
    for (int k=0;k<16;k++){
        int idx = tid + 256*k;         // 4096 float4s
        int d = idx >> 5, c4 = (idx & 31)*4;
        float4 v = *(const float4*)(W + d*C_DIM + c4);
        uint2 u;
        u.x = (uint32)f2b(v.x) | ((uint32)f2b(v.y)<<16);
        u.y = (uint32)f2b(v.z) | ((uint32)f2b(v.w)<<16);
        *(uint2*)(&Ws[d*136 + c4]) = u;
    }
    __syncthreads();
    // write Xf (token-major bf16, coalesced 16B)
    #pragma unroll
    for (int k=0;k<4;k++){
        int idx = tid + 256*k;          // 1024 x 16B
        int row = idx >> 4, c8 = (idx & 15)*8;
        uint4 o = *(const uint4*)(&Xs[row*136 + c8]);
        *(uint4*)(Xf + (size_t)(t0 + row)*C_DIM + c8) = o;
    }
    // sq[token] = sum_c xf^2
    {
        int tok = tid >> 2, p = tid & 3;
        const ushort_t* xr = &Xs[tok*136 + p*32];
        float sacc = 0.f;
        #pragma unroll
        for (int i=0;i<16;i++){
            uint32 u = *(const uint32*)(&xr[i*2]);
            float v0 = __uint_as_float(u<<16);
            float v1 = __uint_as_float(u & 0xffff0000u);
            sacc = fmaf(v0, v0, sacc);
            sacc = fmaf(v1, v1, sacc);
        }
        sacc += __shfl_xor(sacc, 1);
        sacc += __shfl_xor(sacc, 2);
        if (p == 0) sq[t0 + tok] = sacc;
    }
    // MFMA: y[tok][d] = sum_c Xs[tok][c] * Ws[d][c]
    int wv = tid >> 6, lane = tid & 63;
    int qd = lane >> 4, m = lane & 15;
    f32x4 acc[8] = {{0,0,0,0},{0,0,0,0},{0,0,0,0},{0,0,0,0},
                    {0,0,0,0},{0,0,0,0},{0,0,0,0},{0,0,0,0}};
    #pragma unroll
    for (int kc=0;kc<4;kc++){
        bf16x8 af = *(const bf16x8*)(&Xs[(wv*16 + m)*136 + kc*32 + qd*8]);
        #pragma unroll
        for (int ct=0;ct<8;ct++){
            bf16x8 bfr = *(const bf16x8*)(&Ws[(ct*16+m)*136 + kc*32 + qd*8]);
            acc[ct] = __builtin_amdgcn_mfma_f32_16x16x32_bf16(af, bfr, acc[ct], 0, 0, 0);
        }
    }
    int row = t0 + wv*16 + qd*4;
    #pragma unroll
    for (int ct=0;ct<8;ct++){
        int d = ct*16 + m;
        float bias = bfc[d];
        #pragma unroll
        for (int r=0;r<4;r++)
            Yf[(size_t)(row + r)*C_DIM + d] = acc[ct][r] + bias;
    }
}

// K2: G = Xf·Xf^T, 128x64 tile per block; bitpack (d2 < 64) into Hb[row][64 words]
__global__ __launch_bounds__(256) void k_gram(const ushort_t* __restrict__ Xf,
                                              const float* __restrict__ sq,
                                              u64* __restrict__ Hb){
    __shared__ ushort_t Al[128*136];
    __shared__ ushort_t Bl[64*136];
    int tid = threadIdx.x;
    int i0 = blockIdx.x * 128, j0 = blockIdx.y * 64, b = blockIdx.z;
    const ushort_t* XfA = Xf + (size_t)(b*N_TOK + i0)*C_DIM;
    const ushort_t* XfB = Xf + (size_t)(b*N_TOK + j0)*C_DIM;
    #pragma unroll
    for (int k=0;k<8;k++){
        int q = tid + 256*k;            // 2048 x 16B : 128 rows
        int row = q >> 4, cp = (q & 15)*8;
        *(uint4*)(&Al[row*136 + cp]) = *(const uint4*)(XfA + row*C_DIM + cp);
    }
    #pragma unroll
    for (int k=0;k<4;k++){
        int q = tid + 256*k;            // 1024 x 16B : 64 rows
        int row = q >> 4, cp = (q & 15)*8;
        *(uint4*)(&Bl[row*136 + cp]) = *(const uint4*)(XfB + row*C_DIM + cp);
    }
    __syncthreads();
    int wv = tid >> 6, lane = tid & 63;
    int qd = lane >> 4, m = lane & 15;
    f32x4 acc[2][4] = {{{0,0,0,0},{0,0,0,0},{0,0,0,0},{0,0,0,0}},
                       {{0,0,0,0},{0,0,0,0},{0,0,0,0},{0,0,0,0}}};
    #pragma unroll
    for (int kc=0;kc<4;kc++){
        bf16x8 a0 = *(const bf16x8*)(&Al[(wv*32 +      m)*136 + kc*32 + qd*8]);
        bf16x8 a1 = *(const bf16x8*)(&Al[(wv*32 + 16 + m)*136 + kc*32 + qd*8]);
        #pragma unroll
        for (int ct=0;ct<4;ct++){
            bf16x8 bfr = *(const bf16x8*)(&Bl[(ct*16+m)*136 + kc*32 + qd*8]);
            acc[0][ct] = __builtin_amdgcn_mfma_f32_16x16x32_bf16(a0, bfr, acc[0][ct], 0, 0, 0);
            acc[1][ct] = __builtin_amdgcn_mfma_f32_16x16x32_bf16(a1, bfr, acc[1][ct], 0, 0, 0);
        }
    }
    float sqj[4];
    #pragma unroll
    for (int ct=0;ct<4;ct++) sqj[ct] = sq[b*N_TOK + j0 + ct*16 + m];
    #pragma unroll
    for (int rt=0;rt<2;rt++){
        int ib = i0 + wv*32 + rt*16 + qd*4;
        float sqi[4];
        #pragma unroll
        for (int r=0;r<4;r++) sqi[r] = sq[b*N_TOK + ib + r];
        #pragma unroll
        for (int r=0;r<4;r++){
            u64 bits = 0;
            #pragma unroll
            for (int ct=0;ct<4;ct++){
                float d2 = sqi[r] + sqj[ct] - 2.0f*acc[rt][ct][r];
                if (d2 < THRESH2) bits |= (u64)1 << (ct*16 + m);
            }
            bits |= shfl_xor_u64(bits, 1);
            bits |= shfl_xor_u64(bits, 2);
            bits |= shfl_xor_u64(bits, 4);
            bits |= shfl_xor_u64(bits, 8);
            if (m == 0) Hb[(size_t)(b*N_TOK + ib + r)*64 + blockIdx.y] = bits;
        }
    }
}

// K3: sparse aggregation. One wave per output row.
// MODE 0: Out = (H @ V) / rowsum          (V = Yf -> Ef)
// MODE 1: Out = Yf + (H @ V) / rowsum     (V = Ef -> Xe)
template<int MODE>
__global__ __launch_bounds__(256) void k_aggs(const u64* __restrict__ Hb,
                                              const float* __restrict__ V,
                                              const float* __restrict__ Yf,
                                              float* __restrict__ Out){
    int tid = threadIdx.x;
    int wv = tid >> 6, lane = tid & 63;
    int row = blockIdx.x * 4 + wv;          // [0, 8192)
    int b = row >> 12;
    u64 myw = Hb[(size_t)row*64 + lane];
    int cnt = __builtin_popcountll(myw);
    cnt += __shfl_xor(cnt, 1);
    cnt += __shfl_xor(cnt, 2);
    cnt += __shfl_xor(cnt, 4);
    cnt += __shfl_xor(cnt, 8);
    cnt += __shfl_xor(cnt, 16);
    cnt += __shfl_xor(cnt, 32);
    float acc0 = 0.f, acc1 = 0.f;
    const float* Vb = V + (size_t)b*N_TOK*C_DIM;
    u64 nz = __ballot(myw != 0);            // which words have any bits
    while (nz){
        int wdi = __builtin_ctzll(nz);
        nz &= nz - 1;
        u64 mw = shfl_u64(myw, wdi);
        while (mw){
            int j = wdi*64 + __builtin_ctzll(mw);
            mw &= mw - 1;
            acc0 += Vb[(size_t)j*C_DIM + lane];
            acc1 += Vb[(size_t)j*C_DIM + lane + 64];
        }
    }
    float norm = (cnt > 0) ? (1.0f/(float)cnt) : 0.0f;
    size_t o = (size_t)row*C_DIM;
    if (MODE == 0){
        Out[o + lane]      = acc0*norm;
        Out[o + lane + 64] = acc1*norm;
    } else {
        Out[o + lane]      = Yf[o + lane]      + acc0*norm;
        Out[o + lane + 64] = Yf[o + lane + 64] + acc1*norm;
    }
}

// K4: per-channel sum & sumsq over all 8192 tokens
__global__ __launch_bounds__(256) void k_bnstats(const float* __restrict__ Xe,
                                                 float* __restrict__ bn){
    __shared__ float r1[256], r2[256];
    int tid = threadIdx.x;
    int c = tid & 127, h = tid >> 7;
    int tb = blockIdx.x * 64;
    float sm = 0.f, ss = 0.f;
    for (int tt = tb + h; tt < tb + 64; tt += 2){
        float v = Xe[(size_t)tt*C_DIM + c];
        sm += v; ss = fmaf(v, v, ss);
    }
    r1[tid] = sm; r2[tid] = ss;
    __syncthreads();
    if (tid < 128){
        atomicAdd(&bn[c],       r1[tid] + r1[tid+128]);
        atomicAdd(&bn[128 + c], r2[tid] + r2[tid+128]);
    }
}

// K5: BN affine + SiLU + transpose back to [B,C,N], fp32 out
__global__ __launch_bounds__(256) void k_out(const float* __restrict__ Xe,
                                             const float* __restrict__ bn,
                                             const float* __restrict__ gamma,
                                             const float* __restrict__ beta,
                                             float* __restrict__ out){
    __shared__ float tile[32][33];
    int tx = threadIdx.x, ty = threadIdx.y;
    int n0 = blockIdx.x*32, c0 = blockIdx.y*32, b = blockIdx.z;
    int c = c0 + tx;
    float inv = 1.0f / (float)NTOT;
    float mean = bn[c] * inv;
    float var  = bn[128 + c]*inv - mean*mean;
    float scale = gamma[c] * rsqrtf(var + 1e-5f);
    float shift = beta[c] - mean*scale;
    #pragma unroll
    for (int k=0;k<4;k++){
        int nl = ty + 8*k;
        float v = Xe[(size_t)(b*N_TOK + n0 + nl)*C_DIM + c];
        v = scale*v + shift;
        float sg = 1.0f/(1.0f + __expf(-v));
        tile[tx][nl] = v * sg;
    }
    __syncthreads();
    #pragma unroll
    for (int k=0;k<4;k++){
        int cl = ty + 8*k;
        out[(size_t)(b*C_DIM + c0 + cl)*N_TOK + n0 + tx] = tile[cl][tx];
    }
}

extern "C" void kernel_launch(void* const* d_in, const int* in_sizes, int n_in,
                              void* d_out, int out_size, void* d_ws, size_t ws_size,
                              hipStream_t stream){
    if (ws_size < WS_NEED) return;
    const float* x     = (const float*)d_in[0];
    const float* W     = (const float*)d_in[1];
    const float* bfc   = (const float*)d_in[2];
    const float* gamma = (const float*)d_in[3];
    const float* beta  = (const float*)d_in[4];
    char* ws = (char*)d_ws;
    ushort_t* Xf = (ushort_t*)(ws + XF_OFF);
    float*    Yf = (float*)(ws + YF_OFF);
    float*    Ef = (float*)(ws + EF_OFF);
    float*    Xe = (float*)(ws + XE_OFF);
    float*    sq = (float*)(ws + SQ_OFF);
    float*    bn = (float*)(ws + BN_OFF);
    u64*      Hb = (u64*)(ws + HB_OFF);
    float* out = (float*)d_out;

    k_fc<<<dim3(128), dim3(256), 0, stream>>>(x, W, bfc, Xf, Yf, sq, bn);
    k_gram<<<dim3(32,64,2), dim3(256), 0, stream>>>(Xf, sq, Hb);
    k_aggs<0><<<dim3(2048), dim3(256), 0, stream>>>(Hb, Yf, Yf, Ef);
    k_aggs<1><<<dim3(2048), dim3(256), 0, stream>>>(Hb, Ef, Yf, Xe);
    k_bnstats<<<dim3(128), dim3(256), 0, stream>>>(Xe, bn);
    k_out<<<dim3(128,4,2), dim3(32,8), 0, stream>>>(Xe, bn, gamma, beta, out);
}

// Round 5
// 112.808 us; speedup vs baseline: 2.6026x; 1.0518x over previous
//
#include <hip/hip_runtime.h>

typedef unsigned short ushort_t;
typedef unsigned int   uint32;
typedef unsigned long long u64;
typedef __bf16 bf16_t;
typedef bf16_t bf16x8 __attribute__((ext_vector_type(8)));
typedef float  f32x4  __attribute__((ext_vector_type(4)));

#define N_TOK 4096
#define C_DIM 128
#define NTOT  8192
#define THRESH2 64.0f

// workspace layout (bytes)
#define XF_OFF  (0u)                      // bf16 [8192][128]  token-major xf (bf16)
#define YF_OFF  (2u<<20)                  // f32  [8192][128]  y
#define EF_OFF  (6u<<20)                  // f32  [8192][128]  E
#define XE_OFF  (10u<<20)                 // f32  [8192][128]  xe
#define SQ_OFF  (14u<<20)                 // f32  [8192]
#define BN_OFF  ((14u<<20) + 32768u)      // f32  [8][256] partitioned bn partials
#define HB_OFF  (16u<<20)                 // u64  [8192][64] bitmask rows
#define WS_NEED ((size_t)(24u<<20))

__device__ __forceinline__ float b2f(ushort_t u){ return __uint_as_float(((uint32)u)<<16); }
__device__ __forceinline__ ushort_t f2b(float f){
    uint32 u = __float_as_uint(f);
    u += 0x7fffu + ((u>>16)&1u);
    return (ushort_t)(u>>16);
}
__device__ __forceinline__ u64 shfl_u64(u64 v, int src){
    uint32 lo = (uint32)v, hi = (uint32)(v>>32);
    lo = __shfl(lo, src); hi = __shfl(hi, src);
    return ((u64)hi<<32)|lo;
}
__device__ __forceinline__ u64 shfl_xor_u64(u64 v, int m){
    uint32 lo = (uint32)v, hi = (uint32)(v>>32);
    lo = __shfl_xor(lo, m); hi = __shfl_xor(hi, m);
    return ((u64)hi<<32)|lo;
}

// K1: fused transpose + FC (MFMA) + sq. Grid (128 token-groups, 2 d-halves).
// Block (tg, dh): 64 tokens x 64 output-dims. dh==0 additionally computes sq
// and zeroes bn partials (block 0,0); Xf write split by dh.
__global__ __launch_bounds__(256) void k_fc(const float* __restrict__ x,
                                            const float* __restrict__ W,
                                            const float* __restrict__ bfc,
                                            ushort_t* __restrict__ Xf,
                                            float* __restrict__ Yf,
                                            float* __restrict__ sq,
                                            float* __restrict__ bnp){
    __shared__ ushort_t Xs[64*136];    // 64 tokens x 128 c (stride 136)
    __shared__ ushort_t Ws[64*136];    // 64 d x 128 c
    int tid = threadIdx.x;
    int t0 = blockIdx.x * 64;          // flat token base (0..8191)
    int dh = blockIdx.y;               // d-half
    int b  = t0 >> 12;
    int n0 = t0 & 4095;
    if (blockIdx.x == 0 && dh == 0){
        #pragma unroll
        for (int k=0;k<8;k++) bnp[tid + 256*k] = 0.f;
    }
    // stage x -> Xs (transposed, bf16)
    const float* xb = x + (size_t)b * C_DIM * N_TOK + n0;
    #pragma unroll
    for (int k=0;k<8;k++){
        int idx = tid + 256*k;         // 2048 float4s = 64 n x 128 c
        int c = idx >> 4, n4 = (idx & 15)*4;
        float4 v = *(const float4*)(xb + (size_t)c*N_TOK + n4);
        Xs[(n4+0)*136 + c] = f2b(v.x);
        Xs[(n4+1)*136 + c] = f2b(v.y);
        Xs[(n4+2)*136 + c] = f2b(v.z);
        Xs[(n4+3)*136 + c] = f2b(v.w);
    }
    // stage W-half -> Ws bf16 (rows d = dh*64 .. +64)
    const float* Wb = W + (size_t)dh*64*C_DIM;
    #pragma unroll
    for (int k=0;k<8;k++){
        int idx = tid + 256*k;         // 2048 float4s = 64 d x 128 c
        int d = idx >> 5, c4 = (idx & 31)*4;
        float4 v = *(const float4*)(Wb + d*C_DIM + c4);
        uint2 u;
        u.x = (uint32)f2b(v.x) | ((uint32)f2b(v.y)<<16);
        u.y = (uint32)f2b(v.z) | ((uint32)f2b(v.w)<<16);
        *(uint2*)(&Ws[d*136 + c4]) = u;
    }
    __syncthreads();
    // write Xf rows [dh*32, dh*32+32) (coalesced 16B)
    #pragma unroll
    for (int k=0;k<2;k++){
        int idx = tid + 256*(k + 2*dh);
        int row = idx >> 4, c8 = (idx & 15)*8;
        uint4 o = *(const uint4*)(&Xs[row*136 + c8]);
        *(uint4*)(Xf + (size_t)(t0 + row)*C_DIM + c8) = o;
    }
    // sq[token] = sum_c xf^2 (dh==0 only)
    if (dh == 0){
        int tok = tid >> 2, p = tid & 3;
        const ushort_t* xr = &Xs[tok*136 + p*32];
        float sacc = 0.f;
        #pragma unroll
        for (int i=0;i<16;i++){
            uint32 u = *(const uint32*)(&xr[i*2]);
            float v0 = __uint_as_float(u<<16);
            float v1 = __uint_as_float(u & 0xffff0000u);
            sacc = fmaf(v0, v0, sacc);
            sacc = fmaf(v1, v1, sacc);
        }
        sacc += __shfl_xor(sacc, 1);
        sacc += __shfl_xor(sacc, 2);
        if (p == 0) sq[t0 + tok] = sacc;
    }
    // MFMA: y[tok][dh*64 + d] = sum_c Xs[tok][c] * Ws[d][c]
    int wv = tid >> 6, lane = tid & 63;
    int qd = lane >> 4, m = lane & 15;
    f32x4 acc[4] = {{0,0,0,0},{0,0,0,0},{0,0,0,0},{0,0,0,0}};
    #pragma unroll
    for (int kc=0;kc<4;kc++){
        bf16x8 af = *(const bf16x8*)(&Xs[(wv*16 + m)*136 + kc*32 + qd*8]);
        #pragma unroll
        for (int ct=0;ct<4;ct++){
            bf16x8 bfr = *(const bf16x8*)(&Ws[(ct*16+m)*136 + kc*32 + qd*8]);
            acc[ct] = __builtin_amdgcn_mfma_f32_16x16x32_bf16(af, bfr, acc[ct], 0, 0, 0);
        }
    }
    int row = t0 + wv*16 + qd*4;
    #pragma unroll
    for (int ct=0;ct<4;ct++){
        int d = dh*64 + ct*16 + m;
        float bias = bfc[d];
        #pragma unroll
        for (int r=0;r<4;r++)
            Yf[(size_t)(row + r)*C_DIM + d] = acc[ct][r] + bias;
    }
}

// K2: symmetric Gram. Only upper-triangle 128x64 tiles (bj >= 2*bi), 1056 per
// batch. Writes straight words + bit-transposed mirror words (H is bitwise
// symmetric: MFMA K-reduction identical for (i,j)/(j,i); d2 formula commutes).
__global__ __launch_bounds__(256) void k_gram(const ushort_t* __restrict__ Xf,
                                              const float* __restrict__ sq,
                                              u64* __restrict__ Hb){
    __shared__ ushort_t Al[128*136];
    __shared__ ushort_t Bl[64*136];
    __shared__ u64 rowW[128];
    __shared__ u64 part[256];
    int tid = threadIdx.x;
    int L = blockIdx.x, b = blockIdx.y;
    // bi = largest with bi*(65-bi) <= L  (start(bi) = sum_{k<bi}(64-2k))
    int bi = (int)((65.0f - sqrtf(4225.0f - 4.0f*(float)L)) * 0.5f);
    while (bi > 0 && bi*(65-bi) > L) --bi;
    while ((bi+1)*(65-(bi+1)) <= L) ++bi;
    int bj = L - bi*(65-bi) + 2*bi;
    int i0 = bi*128, j0 = bj*64;
    const ushort_t* XfA = Xf + (size_t)(b*N_TOK + i0)*C_DIM;
    const ushort_t* XfB = Xf + (size_t)(b*N_TOK + j0)*C_DIM;
    #pragma unroll
    for (int k=0;k<8;k++){
        int q = tid + 256*k;            // 2048 x 16B : 128 rows
        int row = q >> 4, cp = (q & 15)*8;
        *(uint4*)(&Al[row*136 + cp]) = *(const uint4*)(XfA + row*C_DIM + cp);
    }
    #pragma unroll
    for (int k=0;k<4;k++){
        int q = tid + 256*k;            // 1024 x 16B : 64 rows
        int row = q >> 4, cp = (q & 15)*8;
        *(uint4*)(&Bl[row*136 + cp]) = *(const uint4*)(XfB + row*C_DIM + cp);
    }
    __syncthreads();
    int wv = tid >> 6, lane = tid & 63;
    int qd = lane >> 4, m = lane & 15;
    f32x4 acc[2][4] = {{{0,0,0,0},{0,0,0,0},{0,0,0,0},{0,0,0,0}},
                       {{0,0,0,0},{0,0,0,0},{0,0,0,0},{0,0,0,0}}};
    #pragma unroll
    for (int kc=0;kc<4;kc++){
        bf16x8 a0 = *(const bf16x8*)(&Al[(wv*32 +      m)*136 + kc*32 + qd*8]);
        bf16x8 a1 = *(const bf16x8*)(&Al[(wv*32 + 16 + m)*136 + kc*32 + qd*8]);
        #pragma unroll
        for (int ct=0;ct<4;ct++){
            bf16x8 bfr = *(const bf16x8*)(&Bl[(ct*16+m)*136 + kc*32 + qd*8]);
            acc[0][ct] = __builtin_amdgcn_mfma_f32_16x16x32_bf16(a0, bfr, acc[0][ct], 0, 0, 0);
            acc[1][ct] = __builtin_amdgcn_mfma_f32_16x16x32_bf16(a1, bfr, acc[1][ct], 0, 0, 0);
        }
    }
    float sqj[4];
    #pragma unroll
    for (int ct=0;ct<4;ct++) sqj[ct] = sq[b*N_TOK + j0 + ct*16 + m];
    #pragma unroll
    for (int rt=0;rt<2;rt++){
        int lr = wv*32 + rt*16 + qd*4;      // local row base in [0,128)
        int ib = i0 + lr;
        float sqi[4];
        #pragma unroll
        for (int r=0;r<4;r++) sqi[r] = sq[b*N_TOK + ib + r];
        #pragma unroll
        for (int r=0;r<4;r++){
            u64 bits = 0;
            #pragma unroll
            for (int ct=0;ct<4;ct++){
                float d2 = sqi[r] + sqj[ct] - 2.0f*acc[rt][ct][r];
                if (d2 < THRESH2) bits |= (u64)1 << (ct*16 + m);
            }
            bits |= shfl_xor_u64(bits, 1);
            bits |= shfl_xor_u64(bits, 2);
            bits |= shfl_xor_u64(bits, 4);
            bits |= shfl_xor_u64(bits, 8);
            if (m == 0){
                Hb[(size_t)(b*N_TOK + ib + r)*64 + bj] = bits;
                rowW[lr + r] = bits;
            }
        }
    }
    __syncthreads();
    // bit-transpose 128x64 -> 64 rows x 2 words; each thread ORs 32 i's
    {
        int jj = tid & 63, hw = (tid>>6)&1, sub = tid>>7;
        u64 p = 0;
        int ibase = hw*64 + sub*32;
        #pragma unroll 8
        for (int ii=0; ii<32; ii++){
            u64 wrd = rowW[ibase + ii];
            p |= ((wrd >> jj) & 1ull) << (sub*32 + ii);
        }
        part[tid] = p;
    }
    __syncthreads();
    if (tid < 128){
        int jj = tid & 63, hw = tid >> 6;
        u64 wt = part[tid] | part[tid + 128];
        Hb[(size_t)(b*N_TOK + j0 + jj)*64 + 2*bi + hw] = wt;
    }
}

// K3: sparse aggregation. One wave per output row.
// MODE 0: Out = (H @ V) / rowsum          (V = Yf -> Ef)
// MODE 1: Out = Yf + (H @ V) / rowsum     (V = Ef -> Xe)  + bn partial atomics
template<int MODE>
__global__ __launch_bounds__(256) void k_aggs(const u64* __restrict__ Hb,
                                              const float* __restrict__ V,
                                              const float* __restrict__ Yf,
                                              float* __restrict__ Out,
                                              float* __restrict__ bnp){
    __shared__ float r1[4][128];
    __shared__ float r2[4][128];
    int tid = threadIdx.x;
    int wv = tid >> 6, lane = tid & 63;
    int row = blockIdx.x * 4 + wv;          // [0, 8192)
    int b = row >> 12;
    u64 myw = Hb[(size_t)row*64 + lane];
    int cnt = __builtin_popcountll(myw);
    cnt += __shfl_xor(cnt, 1);
    cnt += __shfl_xor(cnt, 2);
    cnt += __shfl_xor(cnt, 4);
    cnt += __shfl_xor(cnt, 8);
    cnt += __shfl_xor(cnt, 16);
    cnt += __shfl_xor(cnt, 32);
    float acc0 = 0.f, acc1 = 0.f;
    const float* Vb = V + (size_t)b*N_TOK*C_DIM;
    u64 nz = __ballot(myw != 0);            // which words have any bits
    while (nz){
        int wdi = __builtin_ctzll(nz);
        nz &= nz - 1;
        u64 mw = shfl_u64(myw, wdi);
        while (mw){
            int j = wdi*64 + __builtin_ctzll(mw);
            mw &= mw - 1;
            acc0 += Vb[(size_t)j*C_DIM + lane];
            acc1 += Vb[(size_t)j*C_DIM + lane + 64];
        }
    }
    float norm = (cnt > 0) ? (1.0f/(float)cnt) : 0.0f;
    size_t o = (size_t)row*C_DIM;
    if (MODE == 0){
        Out[o + lane]      = acc0*norm;
        Out[o + lane + 64] = acc1*norm;
    } else {
        float xe0 = Yf[o + lane]      + acc0*norm;
        float xe1 = Yf[o + lane + 64] + acc1*norm;
        Out[o + lane]      = xe0;
        Out[o + lane + 64] = xe1;
        r1[wv][lane]      = xe0;
        r1[wv][lane + 64] = xe1;
        r2[wv][lane]      = xe0*xe0;
        r2[wv][lane + 64] = xe1*xe1;
        __syncthreads();
        if (tid < 128){
            float s1 = r1[0][tid]+r1[1][tid]+r1[2][tid]+r1[3][tid];
            float s2 = r2[0][tid]+r2[1][tid]+r2[2][tid]+r2[3][tid];
            int prt = blockIdx.x & 7;
            atomicAdd(&bnp[prt*256 + tid],       s1);
            atomicAdd(&bnp[prt*256 + 128 + tid], s2);
        }
    }
}

// K4: BN affine + SiLU + transpose back to [B,C,N], fp32 out.
// Reduces the 8 bn partials inline (redundant across ty; L2-hot).
__global__ __launch_bounds__(256) void k_out(const float* __restrict__ Xe,
                                             const float* __restrict__ bnp,
                                             const float* __restrict__ gamma,
                                             const float* __restrict__ beta,
                                             float* __restrict__ out){
    __shared__ float tile[32][33];
    int tx = threadIdx.x, ty = threadIdx.y;
    int n0 = blockIdx.x*32, c0 = blockIdx.y*32, b = blockIdx.z;
    int c = c0 + tx;
    float s1 = 0.f, s2 = 0.f;
    #pragma unroll
    for (int p=0;p<8;p++){
        s1 += bnp[p*256 + c];
        s2 += bnp[p*256 + 128 + c];
    }
    float inv = 1.0f / (float)NTOT;
    float mean = s1 * inv;
    float var  = s2*inv - mean*mean;
    float scale = gamma[c] * rsqrtf(var + 1e-5f);
    float shift = beta[c] - mean*scale;
    #pragma unroll
    for (int k=0;k<4;k++){
        int nl = ty + 8*k;
        float v = Xe[(size_t)(b*N_TOK + n0 + nl)*C_DIM + c];
        v = scale*v + shift;
        float sg = 1.0f/(1.0f + __expf(-v));
        tile[tx][nl] = v * sg;
    }
    __syncthreads();
    #pragma unroll
    for (int k=0;k<4;k++){
        int cl = ty + 8*k;
        out[(size_t)(b*C_DIM + c0 + cl)*N_TOK + n0 + tx] = tile[cl][tx];
    }
}

extern "C" void kernel_launch(void* const* d_in, const int* in_sizes, int n_in,
                              void* d_out, int out_size, void* d_ws, size_t ws_size,
                              hipStream_t stream){
    if (ws_size < WS_NEED) return;
    const float* x     = (const float*)d_in[0];
    const float* W     = (const float*)d_in[1];
    const float* bfc   = (const float*)d_in[2];
    const float* gamma = (const float*)d_in[3];
    const float* beta  = (const float*)d_in[4];
    char* ws = (char*)d_ws;
    ushort_t* Xf = (ushort_t*)(ws + XF_OFF);
    float*    Yf = (float*)(ws + YF_OFF);
    float*    Ef = (float*)(ws + EF_OFF);
    float*    Xe = (float*)(ws + XE_OFF);
    float*    sq = (float*)(ws + SQ_OFF);
    float*    bnp= (float*)(ws + BN_OFF);
    u64*      Hb = (u64*)(ws + HB_OFF);
    float* out = (float*)d_out;

    k_fc<<<dim3(128,2), dim3(256), 0, stream>>>(x, W, bfc, Xf, Yf, sq, bnp);
    k_gram<<<dim3(1056,2), dim3(256), 0, stream>>>(Xf, sq, Hb);
    k_aggs<0><<<dim3(2048), dim3(256), 0, stream>>>(Hb, Yf, Yf, Ef, bnp);
    k_aggs<1><<<dim3(2048), dim3(256), 0, stream>>>(Hb, Ef, Yf, Xe, bnp);
    k_out<<<dim3(128,4,2), dim3(32,8), 0, stream>>>(Xe, bnp, gamma, beta, out);
}

// Round 7
// 112.259 us; speedup vs baseline: 2.6153x; 1.0049x over previous
//
#include <hip/hip_runtime.h>

typedef unsigned short ushort_t;
typedef unsigned int   uint32;
typedef unsigned long long u64;
typedef __bf16 bf16_t;
typedef bf16_t bf16x8 __attribute__((ext_vector_type(8)));
typedef float  f32x4  __attribute__((ext_vector_type(4)));

#define N_TOK 4096
#define C_DIM 128
#define NTOT  8192
#define THRESH2 64.0f

// workspace layout (bytes)
#define XF_OFF  (0u)                      // bf16 [8192][128]  token-major xf (bf16)
#define YF_OFF  (2u<<20)                  // f32  [8192][128]  y
#define EF_OFF  (6u<<20)                  // f32  [8192][128]  E
#define XE_OFF  (10u<<20)                 // f32  [8192][128]  xe
#define SQ_OFF  (14u<<20)                 // f32  [8192]
#define BN_OFF  ((14u<<20) + 32768u)      // f32  [8][256] partitioned bn partials
#define HB_OFF  (16u<<20)                 // u64  [8192][64] bitmask rows
#define WS_NEED ((size_t)(24u<<20))

__device__ __forceinline__ float b2f(ushort_t u){ return __uint_as_float(((uint32)u)<<16); }
__device__ __forceinline__ ushort_t f2b(float f){
    uint32 u = __float_as_uint(f);
    u += 0x7fffu + ((u>>16)&1u);
    return (ushort_t)(u>>16);
}
__device__ __forceinline__ u64 shfl_u64(u64 v, int src){
    uint32 lo = (uint32)v, hi = (uint32)(v>>32);
    lo = __shfl(lo, src); hi = __shfl(hi, src);
    return ((u64)hi<<32)|lo;
}
__device__ __forceinline__ u64 shfl_xor_u64(u64 v, int m){
    uint32 lo = (uint32)v, hi = (uint32)(v>>32);
    lo = __shfl_xor(lo, m); hi = __shfl_xor(hi, m);
    return ((u64)hi<<32)|lo;
}

// K1: fused transpose + FC (MFMA) + sq. Grid (128 token-groups, 2 d-halves).
// Block (tg, dh): 64 tokens x 64 output-dims. dh==0 additionally computes sq
// and zeroes bn partials (block 0,0); Xf write split by dh.
__global__ __launch_bounds__(256) void k_fc(const float* __restrict__ x,
                                            const float* __restrict__ W,
                                            const float* __restrict__ bfc,
                                            ushort_t* __restrict__ Xf,
                                            float* __restrict__ Yf,
                                            float* __restrict__ sq,
                                            float* __restrict__ bnp){
    __shared__ ushort_t Xs[64*136];    // 64 tokens x 128 c (stride 136)
    __shared__ ushort_t Ws[64*136];    // 64 d x 128 c
    int tid = threadIdx.x;
    int t0 = blockIdx.x * 64;          // flat token base (0..8191)
    int dh = blockIdx.y;               // d-half
    int b  = t0 >> 12;
    int n0 = t0 & 4095;
    if (blockIdx.x == 0 && dh == 0){
        #pragma unroll
        for (int k=0;k<8;k++) bnp[tid + 256*k] = 0.f;
    }
    // stage x -> Xs (transposed, bf16)
    const float* xb = x + (size_t)b * C_DIM * N_TOK + n0;
    #pragma unroll
    for (int k=0;k<8;k++){
        int idx = tid + 256*k;         // 2048 float4s = 64 n x 128 c
        int c = idx >> 4, n4 = (idx & 15)*4;
        float4 v = *(const float4*)(xb + (size_t)c*N_TOK + n4);
        Xs[(n4+0)*136 + c] = f2b(v.x);
        Xs[(n4+1)*136 + c] = f2b(v.y);
        Xs[(n4+2)*136 + c] = f2b(v.z);
        Xs[(n4+3)*136 + c] = f2b(v.w);
    }
    // stage W-half -> Ws bf16 (rows d = dh*64 .. +64)
    const float* Wb = W + (size_t)dh*64*C_DIM;
    #pragma unroll
    for (int k=0;k<8;k++){
        int idx = tid + 256*k;         // 2048 float4s = 64 d x 128 c
        int d = idx >> 5, c4 = (idx & 31)*4;
        float4 v = *(const float4*)(Wb + d*C_DIM + c4);
        uint2 u;
        u.x = (uint32)f2b(v.x) | ((uint32)f2b(v.y)<<16);
        u.y = (uint32)f2b(v.z) | ((uint32)f2b(v.w)<<16);
        *(uint2*)(&Ws[d*136 + c4]) = u;
    }
    __syncthreads();
    // write Xf rows [dh*32, dh*32+32) (coalesced 16B)
    #pragma unroll
    for (int k=0;k<2;k++){
        int idx = tid + 256*(k + 2*dh);
        int row = idx >> 4, c8 = (idx & 15)*8;
        uint4 o = *(const uint4*)(&Xs[row*136 + c8]);
        *(uint4*)(Xf + (size_t)(t0 + row)*C_DIM + c8) = o;
    }
    // sq[token] = sum_c xf^2 (dh==0 only)
    if (dh == 0){
        int tok = tid >> 2, p = tid & 3;
        const ushort_t* xr = &Xs[tok*136 + p*32];
        float sacc = 0.f;
        #pragma unroll
        for (int i=0;i<16;i++){
            uint32 u = *(const uint32*)(&xr[i*2]);
            float v0 = __uint_as_float(u<<16);
            float v1 = __uint_as_float(u & 0xffff0000u);
            sacc = fmaf(v0, v0, sacc);
            sacc = fmaf(v1, v1, sacc);
        }
        sacc += __shfl_xor(sacc, 1);
        sacc += __shfl_xor(sacc, 2);
        if (p == 0) sq[t0 + tok] = sacc;
    }
    // MFMA: y[tok][dh*64 + d] = sum_c Xs[tok][c] * Ws[d][c]
    int wv = tid >> 6, lane = tid & 63;
    int qd = lane >> 4, m = lane & 15;
    f32x4 acc[4] = {{0,0,0,0},{0,0,0,0},{0,0,0,0},{0,0,0,0}};
    #pragma unroll
    for (int kc=0;kc<4;kc++){
        bf16x8 af = *(const bf16x8*)(&Xs[(wv*16 + m)*136 + kc*32 + qd*8]);
        #pragma unroll
        for (int ct=0;ct<4;ct++){
            bf16x8 bfr = *(const bf16x8*)(&Ws[(ct*16+m)*136 + kc*32 + qd*8]);
            acc[ct] = __builtin_amdgcn_mfma_f32_16x16x32_bf16(af, bfr, acc[ct], 0, 0, 0);
        }
    }
    int row = t0 + wv*16 + qd*4;
    #pragma unroll
    for (int ct=0;ct<4;ct++){
        int d = dh*64 + ct*16 + m;
        float bias = bfc[d];
        #pragma unroll
        for (int r=0;r<4;r++)
            Yf[(size_t)(row + r)*C_DIM + d] = acc[ct][r] + bias;
    }
}

// K2: symmetric Gram. Only upper-triangle 128x64 tiles (bj >= 2*bi), 1056 per
// batch. Writes straight words + bit-transposed mirror words (H is bitwise
// symmetric: MFMA K-reduction identical for (i,j)/(j,i); d2 formula commutes).
__global__ __launch_bounds__(256) void k_gram(const ushort_t* __restrict__ Xf,
                                              const float* __restrict__ sq,
                                              u64* __restrict__ Hb){
    __shared__ ushort_t Al[128*136];
    __shared__ ushort_t Bl[64*136];
    __shared__ u64 rowW[128];
    __shared__ u64 part[256];
    int tid = threadIdx.x;
    int L = blockIdx.x, b = blockIdx.y;
    // bi = largest with bi*(65-bi) <= L  (start(bi) = sum_{k<bi}(64-2k))
    int bi = (int)((65.0f - sqrtf(4225.0f - 4.0f*(float)L)) * 0.5f);
    while (bi > 0 && bi*(65-bi) > L) --bi;
    while ((bi+1)*(65-(bi+1)) <= L) ++bi;
    int bj = L - bi*(65-bi) + 2*bi;
    int i0 = bi*128, j0 = bj*64;
    const ushort_t* XfA = Xf + (size_t)(b*N_TOK + i0)*C_DIM;
    const ushort_t* XfB = Xf + (size_t)(b*N_TOK + j0)*C_DIM;
    #pragma unroll
    for (int k=0;k<8;k++){
        int q = tid + 256*k;            // 2048 x 16B : 128 rows
        int row = q >> 4, cp = (q & 15)*8;
        *(uint4*)(&Al[row*136 + cp]) = *(const uint4*)(XfA + row*C_DIM + cp);
    }
    #pragma unroll
    for (int k=0;k<4;k++){
        int q = tid + 256*k;            // 1024 x 16B : 64 rows
        int row = q >> 4, cp = (q & 15)*8;
        *(uint4*)(&Bl[row*136 + cp]) = *(const uint4*)(XfB + row*C_DIM + cp);
    }
    __syncthreads();
    int wv = tid >> 6, lane = tid & 63;
    int qd = lane >> 4, m = lane & 15;
    f32x4 acc[2][4] = {{{0,0,0,0},{0,0,0,0},{0,0,0,0},{0,0,0,0}},
                       {{0,0,0,0},{0,0,0,0},{0,0,0,0},{0,0,0,0}}};
    #pragma unroll
    for (int kc=0;kc<4;kc++){
        bf16x8 a0 = *(const bf16x8*)(&Al[(wv*32 +      m)*136 + kc*32 + qd*8]);
        bf16x8 a1 = *(const bf16x8*)(&Al[(wv*32 + 16 + m)*136 + kc*32 + qd*8]);
        #pragma unroll
        for (int ct=0;ct<4;ct++){
            bf16x8 bfr = *(const bf16x8*)(&Bl[(ct*16+m)*136 + kc*32 + qd*8]);
            acc[0][ct] = __builtin_amdgcn_mfma_f32_16x16x32_bf16(a0, bfr, acc[0][ct], 0, 0, 0);
            acc[1][ct] = __builtin_amdgcn_mfma_f32_16x16x32_bf16(a1, bfr, acc[1][ct], 0, 0, 0);
        }
    }
    float sqj[4];
    #pragma unroll
    for (int ct=0;ct<4;ct++) sqj[ct] = sq[b*N_TOK + j0 + ct*16 + m];
    #pragma unroll
    for (int rt=0;rt<2;rt++){
        int lr = wv*32 + rt*16 + qd*4;      // local row base in [0,128)
        int ib = i0 + lr;
        float sqi[4];
        #pragma unroll
        for (int r=0;r<4;r++) sqi[r] = sq[b*N_TOK + ib + r];
        #pragma unroll
        for (int r=0;r<4;r++){
            u64 bits = 0;
            #pragma unroll
            for (int ct=0;ct<4;ct++){
                float d2 = sqi[r] + sqj[ct] - 2.0f*acc[rt][ct][r];
                if (d2 < THRESH2) bits |= (u64)1 << (ct*16 + m);
            }
            bits |= shfl_xor_u64(bits, 1);
            bits |= shfl_xor_u64(bits, 2);
            bits |= shfl_xor_u64(bits, 4);
            bits |= shfl_xor_u64(bits, 8);
            if (m == 0){
                Hb[(size_t)(b*N_TOK + ib + r)*64 + bj] = bits;
                rowW[lr + r] = bits;
            }
        }
    }
    __syncthreads();
    // bit-transpose 128x64 -> 64 rows x 2 words; each thread ORs 32 i's
    {
        int jj = tid & 63, hw = (tid>>6)&1, sub = tid>>7;
        u64 p = 0;
        int ibase = hw*64 + sub*32;
        #pragma unroll 8
        for (int ii=0; ii<32; ii++){
            u64 wrd = rowW[ibase + ii];
            p |= ((wrd >> jj) & 1ull) << (sub*32 + ii);
        }
        part[tid] = p;
    }
    __syncthreads();
    if (tid < 128){
        int jj = tid & 63, hw = tid >> 6;
        u64 wt = part[tid] | part[tid + 128];
        Hb[(size_t)(b*N_TOK + j0 + jj)*64 + 2*bi + hw] = wt;
    }
}

// K3: sparse aggregation. One wave per output row.
// MODE 0: Out = (H @ V) / rowsum          (V = Yf -> Ef)
// MODE 1: Out = Yf + (H @ V) / rowsum     (V = Ef -> Xe)  + bn partial atomics
template<int MODE>
__global__ __launch_bounds__(256) void k_aggs(const u64* __restrict__ Hb,
                                              const float* __restrict__ V,
                                              const float* __restrict__ Yf,
                                              float* __restrict__ Out,
                                              float* __restrict__ bnp){
    __shared__ float r1[4][128];
    __shared__ float r2[4][128];
    int tid = threadIdx.x;
    int wv = tid >> 6, lane = tid & 63;
    int row = blockIdx.x * 4 + wv;          // [0, 8192)
    int b = row >> 12;
    u64 myw = Hb[(size_t)row*64 + lane];
    int cnt = __builtin_popcountll(myw);
    cnt += __shfl_xor(cnt, 1);
    cnt += __shfl_xor(cnt, 2);
    cnt += __shfl_xor(cnt, 4);
    cnt += __shfl_xor(cnt, 8);
    cnt += __shfl_xor(cnt, 16);
    cnt += __shfl_xor(cnt, 32);
    float acc0 = 0.f, acc1 = 0.f;
    const float* Vb = V + (size_t)b*N_TOK*C_DIM;
    u64 nz = __ballot(myw != 0);            // which words have any bits
    while (nz){
        int wdi = __builtin_ctzll(nz);
        nz &= nz - 1;
        u64 mw = shfl_u64(myw, wdi);
        while (mw){
            int j = wdi*64 + __builtin_ctzll(mw);
            mw &= mw - 1;
            acc0 += Vb[(size_t)j*C_DIM + lane];
            acc1 += Vb[(size_t)j*C_DIM + lane + 64];
        }
    }
    float norm = (cnt > 0) ? (1.0f/(float)cnt) : 0.0f;
    size_t o = (size_t)row*C_DIM;
    if (MODE == 0){
        Out[o + lane]      = acc0*norm;
        Out[o + lane + 64] = acc1*norm;
    } else {
        float xe0 = Yf[o + lane]      + acc0*norm;
        float xe1 = Yf[o + lane + 64] + acc1*norm;
        Out[o + lane]      = xe0;
        Out[o + lane + 64] = xe1;
        r1[wv][lane]      = xe0;
        r1[wv][lane + 64] = xe1;
        r2[wv][lane]      = xe0*xe0;
        r2[wv][lane + 64] = xe1*xe1;
        __syncthreads();
        if (tid < 128){
            float s1 = r1[0][tid]+r1[1][tid]+r1[2][tid]+r1[3][tid];
            float s2 = r2[0][tid]+r2[1][tid]+r2[2][tid]+r2[3][tid];
            int prt = blockIdx.x & 7;
            atomicAdd(&bnp[prt*256 + tid],       s1);
            atomicAdd(&bnp[prt*256 + 128 + tid], s2);
        }
    }
}

// K4: BN affine + SiLU + transpose back to [B,C,N], fp32 out.
// Reduces the 8 bn partials inline (redundant across ty; L2-hot).
__global__ __launch_bounds__(256) void k_out(const float* __restrict__ Xe,
                                             const float* __restrict__ bnp,
                                             const float* __restrict__ gamma,
                                             const float* __restrict__ beta,
                                             float* __restrict__ out){
    __shared__ float tile[32][33];
    int tx = threadIdx.x, ty = threadIdx.y;
    int n0 = blockIdx.x*32, c0 = blockIdx.y*32, b = blockIdx.z;
    int c = c0 + tx;
    float s1 = 0.f, s2 = 0.f;
    #pragma unroll
    for (int p=0;p<8;p++){
        s1 += bnp[p*256 + c];
        s2 += bnp[p*256 + 128 + c];
    }
    float inv = 1.0f / (float)NTOT;
    float mean = s1 * inv;
    float var  = s2*inv - mean*mean;
    float scale = gamma[c] * rsqrtf(var + 1e-5f);
    float shift = beta[c] - mean*scale;
    #pragma unroll
    for (int k=0;k<4;k++){
        int nl = ty + 8*k;
        float v = Xe[(size_t)(b*N_TOK + n0 + nl)*C_DIM + c];
        v = scale*v + shift;
        float sg = 1.0f/(1.0f + __expf(-v));
        tile[tx][nl] = v * sg;
    }
    __syncthreads();
    #pragma unroll
    for (int k=0;k<4;k++){
        int cl = ty + 8*k;
        out[(size_t)(b*C_DIM + c0 + cl)*N_TOK + n0 + tx] = tile[cl][tx];
    }
}

extern "C" void kernel_launch(void* const* d_in, const int* in_sizes, int n_in,
                              void* d_out, int out_size, void* d_ws, size_t ws_size,
                              hipStream_t stream){
    if (ws_size < WS_NEED) return;
    const float* x     = (const float*)d_in[0];
    const float* W     = (const float*)d_in[1];
    const float* bfc   = (const float*)d_in[2];
    const float* gamma = (const float*)d_in[3];
    const float* beta  = (const float*)d_in[4];
    char* ws = (char*)d_ws;
    ushort_t* Xf = (ushort_t*)(ws + XF_OFF);
    float*    Yf = (float*)(ws + YF_OFF);
    float*    Ef = (float*)(ws + EF_OFF);
    float*    Xe = (float*)(ws + XE_OFF);
    float*    sq = (float*)(ws + SQ_OFF);
    float*    bnp= (float*)(ws + BN_OFF);
    u64*      Hb = (u64*)(ws + HB_OFF);
    float* out = (float*)d_out;

    k_fc<<<dim3(128,2), dim3(256), 0, stream>>>(x, W, bfc, Xf, Yf, sq, bnp);
    k_gram<<<dim3(1056,2), dim3(256), 0, stream>>>(Xf, sq, Hb);
    k_aggs<0><<<dim3(2048), dim3(256), 0, stream>>>(Hb, Yf, Yf, Ef, bnp);
    k_aggs<1><<<dim3(2048), dim3(256), 0, stream>>>(Hb, Ef, Yf, Xe, bnp);
    k_out<<<dim3(128,4,2), dim3(32,8), 0, stream>>>(Xe, bnp, gamma, beta, out);
}